// Round 5
// baseline (136.497 us; speedup 1.0000x reference)
//
#include <hip/hip_runtime.h>
#include <hip/hip_bf16.h>
#include <math.h>

using short8 = __attribute__((ext_vector_type(8))) short;
using f32x4  = __attribute__((ext_vector_type(4))) float;
using fv4    = __attribute__((ext_vector_type(4))) float;

#define EMB 768
#define CD  64
#define NSCEN 19
#define KSTEPS 24            // 768 / 32
#define NCHUNKS (25 * 4)     // (24 emb + 1 bag) k-steps x 4 col-tiles, 512 bf16 each
#define BM 128               // rows per block

__device__ __forceinline__ ushort f2bf(float x) {
    unsigned u = __float_as_uint(x);
    u += 0x7FFFu + ((u >> 16) & 1u);   // round-to-nearest-even
    return (ushort)(u >> 16);
}

// packed f32x2 -> bf16x2 (compiler emits v_cvt_pk_bf16_f32)
__device__ __forceinline__ uint cvt2(float x, float y) {
    __hip_bfloat162 h = __float22bfloat162_rn(make_float2(x, y));
    union { __hip_bfloat162 h; uint u; } c;
    c.h = h;
    return c.u;
}

__device__ __forceinline__ fv4 ntl4(const float* p) {
    return __builtin_nontemporal_load((const fv4*)p);
}

// Pre-fragment B = [W1(768x64) ; P(32x64)] into bf16 wave-chunks of 512 elems:
// chunk c = ks*4+ct; element r = lane*8+j  <->  B[k = ks*32+(lane>>4)*8+j][col = ct*16+(lane&15)]
// P[s][col] = sum_d table[s][d] * W1[768+s*16+d][col]  (s<19), else 0.
__global__ void prep_W1T(const float* __restrict__ table,
                         const float* __restrict__ W1,
                         ushort* __restrict__ W1T) {
    int e = blockIdx.x * 256 + threadIdx.x;      // 0 .. 51200
    if (e >= NCHUNKS * 512) return;
    int chunk = e >> 9, r = e & 511;
    int lane = r >> 3, j = r & 7;
    int ks = chunk >> 2, ct = chunk & 3;
    int col = ct * 16 + (lane & 15);
    int k = ks * 32 + ((lane >> 4) << 3) + j;
    float v = 0.f;
    if (k < EMB) {
        v = W1[(size_t)k * CD + col];
    } else {
        int s = k - EMB;
        if (s < NSCEN) {
            for (int d = 0; d < 16; ++d)
                v += table[s * 16 + d] * W1[(size_t)(EMB + s * 16 + d) * CD + col];
        }
    }
    W1T[e] = f2bf(v);
}

__global__ __launch_bounds__(256, 2)
void scorer_mfma(const float* __restrict__ emb,
                 const int* __restrict__ ids,
                 const float* __restrict__ mask,
                 const ushort* __restrict__ W1T,
                 const float* __restrict__ b1,
                 const float* __restrict__ W2,
                 const float* __restrict__ b2,
                 float* __restrict__ out) {
    __shared__ float  bagf[BM][21];   // [.. , 20]=cnt; stride 21 (gcd(21,32)=1)
    __shared__ ushort bagb[BM][32];   // bf16 hist/cnt, zero-padded to K=32

    const int t    = threadIdx.x;
    const int w    = t >> 6;       // wave 0..3, owns rows w*32..w*32+31
    const int lane = t & 63;
    const int lr   = lane & 15;    // A-row / B-col residue
    const int lg   = lane >> 4;    // k-group (8 wide) / C row-group
    const int row0 = blockIdx.x * BM;

    // ---- bag histogram: 2 threads per row, fire-and-forget LDS atomics
    for (int e = t; e < BM * 21; e += 256) ((float*)bagf)[e] = 0.f;
    __syncthreads();
    {
        const int r = t & (BM - 1), half = t >> 7;   // half = 0/1 -> slots 0-15 / 16-31
        const int*   idrow = ids  + (size_t)(row0 + r) * 32 + half * 16;
        const float* mrow  = mask + (size_t)(row0 + r) * 32 + half * 16;
        float cnt = 0.f;
#pragma unroll
        for (int q = 0; q < 4; ++q) {
            int4   i4 = ((const int4*)idrow)[q];
            float4 m4 = ((const float4*)mrow)[q];
            atomicAdd(&bagf[r][i4.x], m4.x);
            atomicAdd(&bagf[r][i4.y], m4.y);
            atomicAdd(&bagf[r][i4.z], m4.z);
            atomicAdd(&bagf[r][i4.w], m4.w);
            cnt += m4.x + m4.y + m4.z + m4.w;
        }
        atomicAdd(&bagf[r][20], cnt);
    }
    __syncthreads();
    if (t < BM) {
        float rc = 1.0f / fmaxf(bagf[t][20], 1.0f);
        union { uint u[16]; short8 s[4]; } cv;
#pragma unroll
        for (int p = 0; p < 16; ++p) {
            float x0 = (2 * p     < NSCEN) ? bagf[t][2 * p] * rc     : 0.f;
            float x1 = (2 * p + 1 < NSCEN) ? bagf[t][2 * p + 1] * rc : 0.f;
            cv.u[p] = cvt2(x0, x1);
        }
#pragma unroll
        for (int q = 0; q < 4; ++q) *(short8*)&bagb[t][q * 8] = cv.s[q];
    }
    __syncthreads();   // last block barrier

    // ---- barrier-free MFMA stream: 32 rows x 64 cols per wave,
    //      A-loads bursted 4 k-steps (512 B/row) at a time for DRAM page locality
    const float*  ap = emb + (size_t)(row0 + w * 32 + lr) * EMB + (lg << 3);
    const ushort* wp = W1T + (lane << 3);

    f32x4 acc[2][4];
#pragma unroll
    for (int i = 0; i < 2; ++i)
#pragma unroll
        for (int j = 0; j < 4; ++j) acc[i][j] = (f32x4)0.f;

    fv4    aG[2][4][2][2];   // [pingpong][ks-in-group][row-tile][half]
    short8 bb[3][4];         // B rotation, depth 2

#define LOADG(dst, gg) do {                                    \
    _Pragma("unroll")                                          \
    for (int _s = 0; _s < 4; ++_s) {                           \
        const float* _p = ap + ((gg) * 4 + _s) * 32;           \
        dst[_s][0][0] = ntl4(_p);                              \
        dst[_s][0][1] = ntl4(_p + 4);                          \
        dst[_s][1][0] = ntl4(_p + 16 * EMB);                   \
        dst[_s][1][1] = ntl4(_p + 16 * EMB + 4);               \
    }                                                          \
} while (0)

#define LOADB(dst, kks) do {                                   \
    const ushort* _q = wp + ((size_t)(kks) << 11);             \
    dst[0] = *(const short8*)(_q);                             \
    dst[1] = *(const short8*)(_q + 512);                       \
    dst[2] = *(const short8*)(_q + 1024);                      \
    dst[3] = *(const short8*)(_q + 1536);                      \
} while (0)

#define STEP(areg, breg) do {                                              \
    short8 _fa[2];                                                         \
    _Pragma("unroll")                                                      \
    for (int _rt = 0; _rt < 2; ++_rt) {                                    \
        union { uint u[4]; short8 s; } _c;                                 \
        _c.u[0] = cvt2(areg[_rt][0][0], areg[_rt][0][1]);                  \
        _c.u[1] = cvt2(areg[_rt][0][2], areg[_rt][0][3]);                  \
        _c.u[2] = cvt2(areg[_rt][1][0], areg[_rt][1][1]);                  \
        _c.u[3] = cvt2(areg[_rt][1][2], areg[_rt][1][3]);                  \
        _fa[_rt] = _c.s;                                                   \
    }                                                                      \
    _Pragma("unroll")                                                      \
    for (int _rt = 0; _rt < 2; ++_rt) {                                    \
        acc[_rt][0] = __builtin_amdgcn_mfma_f32_16x16x32_bf16(_fa[_rt], breg[0], acc[_rt][0], 0, 0, 0); \
        acc[_rt][1] = __builtin_amdgcn_mfma_f32_16x16x32_bf16(_fa[_rt], breg[1], acc[_rt][1], 0, 0, 0); \
        acc[_rt][2] = __builtin_amdgcn_mfma_f32_16x16x32_bf16(_fa[_rt], breg[2], acc[_rt][2], 0, 0, 0); \
        acc[_rt][3] = __builtin_amdgcn_mfma_f32_16x16x32_bf16(_fa[_rt], breg[3], acc[_rt][3], 0, 0, 0); \
    }                                                                      \
} while (0)

    LOADB(bb[0], 0);
    LOADB(bb[1], 1);
    LOADG(aG[0], 0);

#pragma unroll
    for (int g = 0; g < 6; ++g) {
        if (g < 5) LOADG(aG[(g + 1) & 1], g + 1);   // 16-load burst for next group
#pragma unroll
        for (int s = 0; s < 4; ++s) {
            const int ks = g * 4 + s;
            if (ks + 2 <= KSTEPS) LOADB(bb[(ks + 2) % 3], ks + 2);  // depth-2 B
            STEP(aG[g & 1][s], bb[ks % 3]);
        }
    }

    // ---- bag k-step (ks = 24): A from LDS (bf16 direct), B = bb[24%3=0]
    {
        short8 ab[2];
        ab[0] = *(const short8*)&bagb[w * 32 + lr][lg << 3];
        ab[1] = *(const short8*)&bagb[w * 32 + 16 + lr][lg << 3];
#pragma unroll
        for (int rt = 0; rt < 2; ++rt) {
            acc[rt][0] = __builtin_amdgcn_mfma_f32_16x16x32_bf16(ab[rt], bb[0][0], acc[rt][0], 0, 0, 0);
            acc[rt][1] = __builtin_amdgcn_mfma_f32_16x16x32_bf16(ab[rt], bb[0][1], acc[rt][1], 0, 0, 0);
            acc[rt][2] = __builtin_amdgcn_mfma_f32_16x16x32_bf16(ab[rt], bb[0][2], acc[rt][2], 0, 0, 0);
            acc[rt][3] = __builtin_amdgcn_mfma_f32_16x16x32_bf16(ab[rt], bb[0][3], acc[rt][3], 0, 0, 0);
        }
    }

    // ---- epilogue: bias + relu + dot(W2) + tanh
    float b1v[4], w2v[4];
#pragma unroll
    for (int ct = 0; ct < 4; ++ct) {
        int c = ct * 16 + lr;
        b1v[ct] = b1[c];
        w2v[ct] = W2[c];
    }
    const float b2v = b2[0];
#pragma unroll
    for (int rt = 0; rt < 2; ++rt) {
#pragma unroll
        for (int r = 0; r < 4; ++r) {
            float p = 0.f;
#pragma unroll
            for (int ct = 0; ct < 4; ++ct) {
                float h = acc[rt][ct][r] + b1v[ct];
                p += fmaxf(h, 0.f) * w2v[ct];
            }
            p += __shfl_xor(p, 1);
            p += __shfl_xor(p, 2);
            p += __shfl_xor(p, 4);
            p += __shfl_xor(p, 8);
            if (lr == 0)
                out[row0 + w * 32 + rt * 16 + (lg << 2) + r] = tanhf(p + b2v);
        }
    }
#undef LOADG
#undef LOADB
#undef STEP
}

extern "C" void kernel_launch(void* const* d_in, const int* in_sizes, int n_in,
                              void* d_out, int out_size, void* d_ws, size_t ws_size,
                              hipStream_t stream) {
    const float* emb   = (const float*)d_in[0];
    const int*   ids   = (const int*)d_in[1];
    const float* mask  = (const float*)d_in[2];
    const float* table = (const float*)d_in[3];
    const float* W1    = (const float*)d_in[4];
    const float* b1    = (const float*)d_in[5];
    const float* W2    = (const float*)d_in[6];
    const float* b2    = (const float*)d_in[7];
    float* out  = (float*)d_out;
    ushort* W1T = (ushort*)d_ws;   // 51200 bf16 = 100 KB

    prep_W1T<<<200, 256, 0, stream>>>(table, W1, W1T);
    const int nblocks = out_size / BM;   // 1024
    scorer_mfma<<<nblocks, 256, 0, stream>>>(emb, ids, mask, W1T, b1, W2, b2, out);
}

// Round 6
// 105.014 us; speedup vs baseline: 1.2998x; 1.2998x over previous
//
#include <hip/hip_runtime.h>
#include <hip/hip_bf16.h>
#include <math.h>

using short8 = __attribute__((ext_vector_type(8))) short;
using f32x4  = __attribute__((ext_vector_type(4))) float;

#define EMB 768
#define CD  64
#define NSCEN 19
#define NCHUNKS (25 * 4)     // W1T: (24 emb + 1 bag) k-steps x 4 col-tiles, 512 bf16 each
#define BM 64                // rows per block
#define CHUNK 256            // f32 k-elems staged per chunk (3 chunks = 768)
#define ROWP 264             // ushort stride per LDS A-row: 528 B = 33*16 (16B-aligned, odd*16 banks)

__device__ __forceinline__ ushort f2bf(float x) {
    unsigned u = __float_as_uint(x);
    u += 0x7FFFu + ((u >> 16) & 1u);   // RNE
    return (ushort)(u >> 16);
}

// packed f32x2 -> bf16x2 (v_cvt_pk_bf16_f32)
__device__ __forceinline__ uint cvt2(float x, float y) {
    __hip_bfloat162 h = __float22bfloat162_rn(make_float2(x, y));
    union { __hip_bfloat162 h; uint u; } c;
    c.h = h;
    return c.u;
}

// Pre-fragment B = [W1(768x64) ; P(32x64)] into bf16 wave-chunks of 512 elems:
// chunk c = ks*4+ct; element r = lane*8+j  <->  B[k = ks*32+(lane>>4)*8+j][col = ct*16+(lane&15)]
__global__ void prep_W1T(const float* __restrict__ table,
                         const float* __restrict__ W1,
                         ushort* __restrict__ W1T) {
    int e = blockIdx.x * 256 + threadIdx.x;      // 0 .. 51200
    if (e >= NCHUNKS * 512) return;
    int chunk = e >> 9, r = e & 511;
    int lane = r >> 3, j = r & 7;
    int ks = chunk >> 2, ct = chunk & 3;
    int col = ct * 16 + (lane & 15);
    int k = ks * 32 + ((lane >> 4) << 3) + j;
    float v = 0.f;
    if (k < EMB) {
        v = W1[(size_t)k * CD + col];
    } else {
        int s = k - EMB;
        if (s < NSCEN) {
            for (int d = 0; d < 16; ++d)
                v += table[s * 16 + d] * W1[(size_t)(EMB + s * 16 + d) * CD + col];
        }
    }
    W1T[e] = f2bf(v);
}

__global__ __launch_bounds__(256, 2)
void scorer_mfma(const float* __restrict__ emb,
                 const int* __restrict__ ids,
                 const float* __restrict__ mask,
                 const ushort* __restrict__ W1T,
                 const float* __restrict__ b1,
                 const float* __restrict__ W2,
                 const float* __restrict__ b2,
                 float* __restrict__ out) {
    __shared__ ushort Abuf[2][BM][ROWP];   // staged A (bf16), double-buffered chunks
    __shared__ float  bagf[BM][21];        // [..,20]=cnt
    __shared__ ushort bagb[BM][32];        // bf16 hist/cnt, K=32 zero-padded

    const int t    = threadIdx.x;
    const int w    = t >> 6;        // wave 0..3 -> C rows w*16..w*16+15
    const int lane = t & 63;
    const int lr   = lane & 15;
    const int lg   = lane >> 4;
    const int row0 = blockIdx.x * BM;

    // ---- issue stage-loads for chunk 0 first (wave-linear: 1 KB contiguous per inst)
    float4 sreg[16];
#pragma unroll
    for (int i = 0; i < 16; ++i)    // row = i*4 + w, cols [lane*4, +4)
        sreg[i] = *(const float4*)(emb + (size_t)(row0 + i * 4 + w) * EMB + lane * 4);

    // ---- bag histogram (4 threads/row, LDS atomics)
    for (int e = t; e < BM * 21; e += 256) ((float*)bagf)[e] = 0.f;
    __syncthreads();
    {
        const int r = t >> 2, p = t & 3;
        const int*   idrow = ids  + (size_t)(row0 + r) * 32 + p * 8;
        const float* mrow  = mask + (size_t)(row0 + r) * 32 + p * 8;
        float cnt = 0.f;
#pragma unroll
        for (int q = 0; q < 2; ++q) {
            int4   i4 = ((const int4*)idrow)[q];
            float4 m4 = ((const float4*)mrow)[q];
            atomicAdd(&bagf[r][i4.x], m4.x);
            atomicAdd(&bagf[r][i4.y], m4.y);
            atomicAdd(&bagf[r][i4.z], m4.z);
            atomicAdd(&bagf[r][i4.w], m4.w);
            cnt += m4.x + m4.y + m4.z + m4.w;
        }
        atomicAdd(&bagf[r][20], cnt);
    }
    __syncthreads();
    if (t < BM) {
        float rc = 1.0f / fmaxf(bagf[t][20], 1.0f);
        union { uint u[16]; short8 s[4]; } cv;
#pragma unroll
        for (int p = 0; p < 16; ++p) {
            float x0 = (2 * p     < NSCEN) ? bagf[t][2 * p] * rc     : 0.f;
            float x1 = (2 * p + 1 < NSCEN) ? bagf[t][2 * p + 1] * rc : 0.f;
            cv.u[p] = cvt2(x0, x1);
        }
#pragma unroll
        for (int q = 0; q < 4; ++q) *(short8*)&bagb[t][q * 8] = cv.s[q];
    }

    // ---- write chunk 0 to LDS (bf16), then enter pipelined chunk loop
#pragma unroll
    for (int i = 0; i < 16; ++i) {
        uint2 v = make_uint2(cvt2(sreg[i].x, sreg[i].y), cvt2(sreg[i].z, sreg[i].w));
        *(uint2*)&Abuf[0][i * 4 + w][lane * 4] = v;
    }
    __syncthreads();

    const ushort* wp = W1T + (lane << 3);
    f32x4 acc[4];
#pragma unroll
    for (int j = 0; j < 4; ++j) acc[j] = (f32x4)0.f;

    short8 bbA[4], bbB[4];
#define LOADB(dst, kk) do {                                    \
    const ushort* q_ = wp + ((size_t)(kk) << 11);              \
    dst[0] = *(const short8*)(q_);                             \
    dst[1] = *(const short8*)(q_ + 512);                       \
    dst[2] = *(const short8*)(q_ + 1024);                      \
    dst[3] = *(const short8*)(q_ + 1536);                      \
} while (0)

#define MFMA4(a_, b_) do {                                                         \
    acc[0] = __builtin_amdgcn_mfma_f32_16x16x32_bf16(a_, b_[0], acc[0], 0, 0, 0);  \
    acc[1] = __builtin_amdgcn_mfma_f32_16x16x32_bf16(a_, b_[1], acc[1], 0, 0, 0);  \
    acc[2] = __builtin_amdgcn_mfma_f32_16x16x32_bf16(a_, b_[2], acc[2], 0, 0, 0);  \
    acc[3] = __builtin_amdgcn_mfma_f32_16x16x32_bf16(a_, b_[3], acc[3], 0, 0, 0);  \
} while (0)

    LOADB(bbA, 0);

#pragma unroll
    for (int kc = 0; kc < 3; ++kc) {
        const int cb = kc & 1;
        if (kc < 2) {   // issue next chunk's global loads early (hide under compute)
#pragma unroll
            for (int i = 0; i < 16; ++i)
                sreg[i] = *(const float4*)(emb + (size_t)(row0 + i * 4 + w) * EMB
                                           + (kc + 1) * CHUNK + lane * 4);
        }
#pragma unroll
        for (int ks = 0; ks < 8; ++ks) {
            const int ksg = kc * 8 + ks;
            short8 a = *(const short8*)&Abuf[cb][w * 16 + lr][ks * 32 + lg * 8];
            if ((ks & 1) == 0) {
                LOADB(bbB, ksg + 1);
                MFMA4(a, bbA);
            } else {
                LOADB(bbA, ksg + 1);   // max arg = 24 (bag chunk) at ksg=23
                MFMA4(a, bbB);
            }
        }
        if (kc < 2) {   // write-late: convert + ds_write next chunk
#pragma unroll
            for (int i = 0; i < 16; ++i) {
                uint2 v = make_uint2(cvt2(sreg[i].x, sreg[i].y), cvt2(sreg[i].z, sreg[i].w));
                *(uint2*)&Abuf[cb ^ 1][i * 4 + w][lane * 4] = v;
            }
        }
        __syncthreads();
    }

    // ---- bag k-step (ksg=24): A from bagb, B = bbA (prefetched at ksg=23)
    {
        short8 ab = *(const short8*)&bagb[w * 16 + lr][lg * 8];
        MFMA4(ab, bbA);
    }

    // ---- epilogue: bias + relu + dot(W2) + tanh; reduce over lr (16 lanes)
    float b1v[4], w2v[4];
#pragma unroll
    for (int ct = 0; ct < 4; ++ct) {
        int c = ct * 16 + lr;
        b1v[ct] = b1[c];
        w2v[ct] = W2[c];
    }
    const float b2v = b2[0];
#pragma unroll
    for (int r = 0; r < 4; ++r) {
        float p = 0.f;
#pragma unroll
        for (int ct = 0; ct < 4; ++ct) {
            float h = acc[ct][r] + b1v[ct];
            p += fmaxf(h, 0.f) * w2v[ct];
        }
        p += __shfl_xor(p, 1);
        p += __shfl_xor(p, 2);
        p += __shfl_xor(p, 4);
        p += __shfl_xor(p, 8);
        if (lr == 0)
            out[row0 + w * 16 + lg * 4 + r] = tanhf(p + b2v);
    }
#undef LOADB
#undef MFMA4
}

extern "C" void kernel_launch(void* const* d_in, const int* in_sizes, int n_in,
                              void* d_out, int out_size, void* d_ws, size_t ws_size,
                              hipStream_t stream) {
    const float* emb   = (const float*)d_in[0];
    const int*   ids   = (const int*)d_in[1];
    const float* mask  = (const float*)d_in[2];
    const float* table = (const float*)d_in[3];
    const float* W1    = (const float*)d_in[4];
    const float* b1    = (const float*)d_in[5];
    const float* W2    = (const float*)d_in[6];
    const float* b2    = (const float*)d_in[7];
    float* out  = (float*)d_out;
    ushort* W1T = (ushort*)d_ws;   // 51200 bf16 = 100 KB

    prep_W1T<<<200, 256, 0, stream>>>(table, W1, W1T);
    const int nblocks = out_size / BM;   // 2048
    scorer_mfma<<<nblocks, 256, 0, stream>>>(emb, ids, mask, W1T, b1, W2, b2, out);
}